// Round 6
// baseline (352.453 us; speedup 1.0000x reference)
//
#include <hip/hip_runtime.h>

typedef float v2f __attribute__((ext_vector_type(2)));

namespace {
constexpr int W = 1024;
constexpr int H = 1024;
constexpr int NIMG = 32;
constexpr int SROWS = 32;            // output rows per block strip
constexpr int NSTRIP = H / SROWS;    // 32 -> grid 1024 blocks of 512 thr
constexpr int BLOCK = 512;           // 512 threads * 2 cols = 1024 cols
// linear pair buffer: 8 zero-pad pair-cols each side of 1024 -> 1040 pairs
// = 520 float4. One float4 per thread -> writes AND reads are naturally
// consecutive; no plane split needed.
constexpr int NF4 = 520;

constexpr float C1 = 0.0004f;        // (0.01*2)^2
constexpr float C2 = 0.0036f;        // (0.03*2)^2

// normalized gaussian, sigma=1.5, win=11 (symmetric: GW[k]==GW[10-k])
constexpr float GW[11] = {
    0.00102838f, 0.00759876f, 0.03600077f, 0.10936070f, 0.21300554f,
    0.26601172f,
    0.21300554f, 0.10936070f, 0.03600077f, 0.00759876f, 0.00102838f};
}  // namespace

// Block-wide barrier that only waits for LDS (lgkmcnt), NOT vmcnt: the pf
// global load stays in flight across barriers (no collective HBM drain).
__device__ __forceinline__ void lds_barrier() {
  asm volatile("s_waitcnt lgkmcnt(0)" ::: "memory");
  __builtin_amdgcn_s_barrier();
  asm volatile("" ::: "memory");
}

// Load one row (2 cols/thread), packed pairs (u,v) = (x+y, x-y).
// y is block-uniform -> uniform branch, no per-lane masking.
__device__ __forceinline__ void load_uv(const float2* __restrict__ p1,
                                        const float2* __restrict__ p2, int y,
                                        int tid, v2f uv[2]) {
  if ((unsigned)y < (unsigned)H) {
    const float2 a = p1[y * (W / 2) + tid];
    const float2 b = p2[y * (W / 2) + tid];
    uv[0] = (v2f){a.x + b.x, a.x - b.x};
    uv[1] = (v2f){a.y + b.y, a.y - b.y};
  } else {
    uv[0] = (v2f){0.f, 0.f};
    uv[1] = (v2f){0.f, 0.f};
  }
}

// 11-tap horizontal blur, 2 output pair-cols per thread.
// B[tid+1+e] (e=0..6) holds pairs 2tid+2+2e, 2tid+3+2e; t[s] = pair 2tid+2+s.
// Output m (image pair-col p=2tid+m): sum_k GW[k]*t[m+1+k].
__device__ __forceinline__ void hblur(const float4* __restrict__ B, int tid,
                                      v2f h[2]) {
  v2f t[14];
#pragma unroll
  for (int e = 0; e < 7; ++e) {
    const float4 r = B[tid + 1 + e];
    t[2 * e + 0] = (v2f){r.x, r.y};
    t[2 * e + 1] = (v2f){r.z, r.w};
  }
#pragma unroll
  for (int m = 0; m < 2; ++m) {
    v2f s = (v2f){GW[0], GW[0]} * t[m + 1];
#pragma unroll
    for (int k = 1; k < 11; ++k)
      s = __builtin_elementwise_fma((v2f){GW[k], GW[k]}, t[m + 1 + k], s);
    h[m] = s;
  }
}

// Sum of SSIM map values over the strip; atomicAdd into ws[0] (double).
// Register-footprint design (rounds 0-5 evidence): occupancy is capped by
// TOTAL per-wave regs (unified VGPR+AGPR), not LDS — the 4-col/thread ring
// (88 floats) forced ~128 regs/wave -> 4 waves/SIMD -> occ 36% regardless of
// LDS. Halving cols/thread halves the ring (44) -> target ~96 regs/wave ->
// 5 waves/SIMD. launch_bounds(512,5): budget 102 regs (roomy; bound=8 at
// 4-col collapsed the allocator to 32 VGPR + 3.4GB scratch — round 4).
__global__ __launch_bounds__(BLOCK, 5) void ssim_main(
    const float* __restrict__ img1, const float* __restrict__ img2,
    double* __restrict__ ws) {
  // single-buffered linear pair buffers (lgkm-only barriers x2 per row):
  // bufUV = (blur_v(u), blur_v(v)) pairs; bufSQ = (blur_v(u^2), blur_v(v^2))
  __shared__ __align__(16) float4 bufUV[NF4];
  __shared__ __align__(16) float4 bufSQ[NF4];
  __shared__ float red[BLOCK / 64];

  const int tid = threadIdx.x;
  const int bid = blockIdx.x;
  const int img = bid / NSTRIP;
  const int strip = bid % NSTRIP;
  const int ys = strip * SROWS;

  const float2* p1 =
      reinterpret_cast<const float2*>(img1) + (size_t)img * (W / 2) * H;
  const float2* p2 =
      reinterpret_cast<const float2*>(img2) + (size_t)img * (W / 2) * H;

  // zero pad: float4 slots {0..3, 516..519} in both buffers
  if (tid < 4) {
    const float4 z = make_float4(0.f, 0.f, 0.f, 0.f);
    bufUV[tid] = z;
    bufUV[516 + tid] = z;
    bufSQ[tid] = z;
    bufSQ[516 + tid] = z;
  }

  // shift ring: rows r-5..r+4 in ruv[0..9]; pf prefetches row r+5
  // (round-0 ordering: commit pf at loop top, issue next pf before vblur —
  //  the only schedule measured NOT to spill; reorderings cost 17-64MB scratch)
  v2f ruv[11][2];
#pragma unroll
  for (int s = 0; s < 10; ++s) load_uv(p1, p2, ys - 5 + s, tid, ruv[s]);
  v2f pf[2];
  load_uv(p1, p2, ys + 5, tid, pf);

  float acc = 0.f;

  for (int ii = 0; ii < SROWS; ++ii) {
    // commit prefetched row r+5, start prefetch of row r+6.
    // The new pf load stays in flight across lds_barrier() (no vmcnt drain)
    // and completes during hblur+ssim, waited per-wave at next commit.
    ruv[10][0] = pf[0];
    ruv[10][1] = pf[1];
    load_uv(p1, p2, ys + ii + 6, tid, pf);

    // vertical 11-tap blur, symmetric-pair form (GW[k]==GW[10-k]):
    // 28 pk-ops/col instead of 33.
    v2f buv[2], bsq[2];
    const v2f g5 = (v2f){GW[5], GW[5]};
#pragma unroll
    for (int c = 0; c < 2; ++c) {
      const v2f x5 = ruv[5][c];
      v2f b = g5 * x5;
      v2f s = g5 * (x5 * x5);
#pragma unroll
      for (int k = 0; k < 5; ++k) {
        const v2f gk = (v2f){GW[k], GW[k]};
        const v2f xa = ruv[k][c];
        const v2f xb = ruv[10 - k][c];
        const v2f p = xa + xb;                              // pk_add
        b = __builtin_elementwise_fma(gk, p, b);            // pk_fma
        const v2f q = __builtin_elementwise_fma(xb, xb, xa * xa);
        s = __builtin_elementwise_fma(gk, q, s);
      }
      buv[c] = b;
      bsq[c] = s;
    }

    // barrier 1: previous iteration's hblur reads must finish before we
    // overwrite the single buffer (placed right before the stores so the
    // reads->here gap absorbs the wait).
    lds_barrier();

    // one float4 per thread -> naturally consecutive stores, conflict-free
    bufUV[tid + 4] = make_float4(buv[0].x, buv[0].y, buv[1].x, buv[1].y);
    bufSQ[tid + 4] = make_float4(bsq[0].x, bsq[0].y, bsq[1].x, bsq[1].y);

    lds_barrier();  // barrier 2: stores visible to all waves

    v2f huv[2], hsq[2];
    hblur(bufUV, tid, huv);
    hblur(bufSQ, tid, hsq);

    // ssim: BU=mu1+mu2, BV=mu1-mu2, BU2=blur((x+y)^2), BV2=blur((x-y)^2)
#pragma unroll
    for (int m = 0; m < 2; ++m) {
      const float BU = huv[m].x, BV = huv[m].y;
      const float BU2 = hsq[m].x, BV2 = hsq[m].y;
      const float P = BU * BU, Q = BV * BV;
      const float PmQ = P - Q, PpQ = P + Q;
      const float An = fmaf(0.5f, PmQ, C1);                // 2*mu1*mu2+C1
      const float Bn = fmaf(0.5f, (BU2 - BV2) - PmQ, C2);  // 2*sigma12+C2
      const float Cd = fmaf(0.5f, PpQ, C1);                // mu1^2+mu2^2+C1
      const float Dd = fmaf(0.5f, (BU2 + BV2) - PpQ, C2);  // s1+s2+C2
      const float num = An * Bn;
      const float den = Cd * Dd;  // >= C1*C2 > 0
      float r = __builtin_amdgcn_rcpf(den);
      r = r * fmaf(-den, r, 2.f);  // one Newton step
      acc = fmaf(num, r, acc);
    }

    // shift the ring (packed 64-bit moves)
#pragma unroll
    for (int k = 0; k < 10; ++k) {
      ruv[k][0] = ruv[k + 1][0];
      ruv[k][1] = ruv[k + 1][1];
    }
  }

  // block reduction -> global double accumulator
#pragma unroll
  for (int off = 32; off > 0; off >>= 1) acc += __shfl_down(acc, off, 64);
  if ((tid & 63) == 0) red[tid >> 6] = acc;
  __syncthreads();
  if (tid == 0) {
    float t = 0.f;
#pragma unroll
    for (int wv = 0; wv < BLOCK / 64; ++wv) t += red[wv];
    atomicAdd(ws, (double)t);
  }
}

__global__ void ssim_fin(const double* __restrict__ ws,
                         float* __restrict__ out) {
  out[0] =
      1.0f - (float)(ws[0] * (1.0 / ((double)NIMG * (double)W * (double)H)));
}

extern "C" void kernel_launch(void* const* d_in, const int* in_sizes, int n_in,
                              void* d_out, int out_size, void* d_ws,
                              size_t ws_size, hipStream_t stream) {
  const float* img1 = (const float*)d_in[0];
  const float* img2 = (const float*)d_in[1];
  float* out = (float*)d_out;
  double* ws = (double*)d_ws;

  hipMemsetAsync(d_ws, 0, sizeof(double), stream);
  ssim_main<<<NIMG * NSTRIP, BLOCK, 0, stream>>>(img1, img2, ws);
  ssim_fin<<<1, 1, 0, stream>>>(ws, out);
}

// Round 8
// 343.942 us; speedup vs baseline: 1.0247x; 1.0247x over previous
//
#include <hip/hip_runtime.h>

typedef float v2f __attribute__((ext_vector_type(2)));

namespace {
constexpr int W = 1024;
constexpr int H = 1024;
constexpr int NIMG = 32;
constexpr int SROWS = 16;            // output rows per block strip
constexpr int NSTRIP = H / SROWS;    // 64 -> grid 2048 = 8 blocks/CU avail
constexpr int BLOCK = 256;           // 256 threads * 4 cols = 1024 cols
// pair-array: 8 zero-pad pair-cols each side of 1024 -> 1040 v2f = 520 float4,
// split into two planes of 260 float4 at float4 granularity.
constexpr int PLANE4 = 260;          // float4 slots per plane

constexpr float C1 = 0.0004f;        // (0.01*2)^2
constexpr float C2 = 0.0036f;        // (0.03*2)^2

// normalized gaussian, sigma=1.5, win=11 (symmetric: GW[k]==GW[10-k])
constexpr float GW[11] = {
    0.00102838f, 0.00759876f, 0.03600077f, 0.10936070f, 0.21300554f,
    0.26601172f,
    0.21300554f, 0.10936070f, 0.03600077f, 0.00759876f, 0.00102838f};
}  // namespace

// Block-wide barrier that only waits for LDS (lgkmcnt), NOT vmcnt: the pf
// global load stays in flight across barriers (no collective HBM drain).
__device__ __forceinline__ void lds_barrier() {
  asm volatile("s_waitcnt lgkmcnt(0)" ::: "memory");
  __builtin_amdgcn_s_barrier();
  asm volatile("" ::: "memory");
}

// pack two f32 -> one u32 of 2 bf16 (RNE). lo -> low16, hi -> high16.
__device__ __forceinline__ unsigned pk_bf16(float lo, float hi) {
  unsigned r;
  asm("v_cvt_pk_bf16_f32 %0, %1, %2" : "=v"(r) : "v"(lo), "v"(hi));
  return r;
}

// unpack u32 of 2 bf16 -> v2f{lo,hi} (bf16->f32 is a 16-bit shift)
__device__ __forceinline__ v2f unpk(unsigned x) {
  v2f r;
  r.x = __uint_as_float(x << 16);
  r.y = __uint_as_float(x & 0xffff0000u);
  return r;
}

// Load one row, compute (u,v)=(x+y,x-y) per col, pack as bf16 col-pairs:
// out = {pk(u0,u1), pk(u2,u3), pk(v0,v1), pk(v2,v3)}  (4 u32 = the whole row)
// Ring compression rationale (rounds 0-6): residency is capped by total
// regs/wave (102..128 with the 88-float f32 ring); bf16 ring = 44 u32
// -> ~95 total -> 5 waves/SIMD instead of 4, with LDS ops unchanged.
__device__ __forceinline__ void load_uv_pk(const float4* __restrict__ p1,
                                           const float4* __restrict__ p2,
                                           int y, int tid, unsigned o[4]) {
  if ((unsigned)y < (unsigned)H) {
    const float4 a = p1[y * (W / 4) + tid];
    const float4 b = p2[y * (W / 4) + tid];
    o[0] = pk_bf16(a.x + b.x, a.y + b.y);  // u0,u1
    o[1] = pk_bf16(a.z + b.z, a.w + b.w);  // u2,u3
    o[2] = pk_bf16(a.x - b.x, a.y - b.y);  // v0,v1
    o[3] = pk_bf16(a.z - b.z, a.w - b.w);  // v2,v3
  } else {
#pragma unroll
    for (int c = 0; c < 4; ++c) o[c] = 0u;
  }
}

// 11-tap horizontal blur over a pre-paired 16-pair window read from the
// two conflict-free planes (f32 - no further precision loss after vblur).
__device__ __forceinline__ void hblur(const float4* __restrict__ P0,
                                      const float4* __restrict__ P1, int tid,
                                      v2f h[4]) {
  v2f t[16];
#pragma unroll
  for (int e = 0; e < 8; ++e) {
    // original pair-float4 j = 2t+1+e; odd j -> P0[(j-1)/2], even -> P1[j/2]
    const float4 r = (e & 1) ? P0[tid + (e + 1) / 2] : P1[tid + e / 2];
    t[2 * e + 0] = (v2f){r.x, r.y};
    t[2 * e + 1] = (v2f){r.z, r.w};
  }
#pragma unroll
  for (int m = 0; m < 4; ++m) {
    v2f s = (v2f){GW[0], GW[0]} * t[m + 1];
#pragma unroll
    for (int k = 1; k < 11; ++k)
      s = __builtin_elementwise_fma((v2f){GW[k], GW[k]}, t[m + 1 + k], s);
    h[m] = s;
  }
}

// Sum of SSIM map values over the strip; atomicAdd into ws[0] (double).
// launch_bounds(256,5): reg budget 102 (feasible: ~95 estimated need; bound=8
// at the f32 ring was infeasible -> 32 VGPR + 3.4GB scratch, round 4).
// 16.9KB LDS (9 blocks/CU) + grid 2048 (8 blocks/CU) -> residency is set by
// the 5-waves/SIMD reg budget = 20 waves/CU (was 16).
__global__ __launch_bounds__(BLOCK, 5) void ssim_main(
    const float* __restrict__ img1, const float* __restrict__ img2,
    double* __restrict__ ws) {
  // single-buffered, plane-split pair buffers (two lgkm-barriers/row):
  // bufUV = (blur_v(u), blur_v(v)) pairs; bufSQ = (blur_v(u^2), blur_v(v^2))
  __shared__ __align__(16) v2f bufUV[2][2 * PLANE4];
  __shared__ __align__(16) v2f bufSQ[2][2 * PLANE4];
  __shared__ float red[BLOCK / 64];

  const int tid = threadIdx.x;
  const int bid = blockIdx.x;
  const int img = bid / NSTRIP;
  const int strip = bid % NSTRIP;
  const int ys = strip * SROWS;

  const float4* p1 =
      reinterpret_cast<const float4*>(img1) + (size_t)img * (W / 4) * H;
  const float4* p2 =
      reinterpret_cast<const float4*>(img2) + (size_t)img * (W / 4) * H;

  // zero pad slots: planes P0/P1 slots {0,1,258,259}, both buffers
  if (tid < 16) {
    const int b = tid & 1, pl = (tid >> 1) & 1, si = tid >> 2;
    const int slot = (si & 1) + ((si >> 1) ? 258 : 0);
    float4* p = reinterpret_cast<float4*>(b ? bufSQ[pl] : bufUV[pl]);
    p[slot] = make_float4(0.f, 0.f, 0.f, 0.f);
  }

  // bf16 shift ring: rows r-5..r+4 in ruv[0..9]; pf prefetches row r+5
  // (round-0 ordering: commit pf at loop top, issue next pf before vblur —
  //  the only schedule measured NOT to spill; reorderings cost 17-64MB scratch)
  unsigned ruv[11][4];
#pragma unroll
  for (int s = 0; s < 10; ++s) load_uv_pk(p1, p2, ys - 5 + s, tid, ruv[s]);
  unsigned pf[4];
  load_uv_pk(p1, p2, ys + 5, tid, pf);

  float acc = 0.f;

  for (int ii = 0; ii < SROWS; ++ii) {
    // commit prefetched row r+5, start prefetch of row r+6.
    // The new pf load stays in flight across lds_barrier() (no vmcnt drain)
    // and completes during hblur+ssim, waited per-wave at next commit.
#pragma unroll
    for (int c = 0; c < 4; ++c) ruv[10][c] = pf[c];
    load_uv_pk(p1, p2, ys + ii + 6, tid, pf);

    // vertical 11-tap blur, symmetric-pair form, per bf16 col-pair channel:
    // ch 0,1 = u-pairs (c01,c23); ch 2,3 = v-pairs. Packed v2f math over the
    // two cols of the channel (identical arithmetic to the (u,v) packing).
    v2f bb[4], ss[4];
    const v2f g5 = (v2f){GW[5], GW[5]};
#pragma unroll
    for (int ch = 0; ch < 4; ++ch) {
      const v2f x5 = unpk(ruv[5][ch]);
      v2f b = g5 * x5;
      v2f s = g5 * (x5 * x5);
#pragma unroll
      for (int k = 0; k < 5; ++k) {
        const v2f gk = (v2f){GW[k], GW[k]};
        const v2f xa = unpk(ruv[k][ch]);
        const v2f xb = unpk(ruv[10 - k][ch]);
        const v2f p = xa + xb;                              // pk_add
        b = __builtin_elementwise_fma(gk, p, b);            // pk_fma
        const v2f q = __builtin_elementwise_fma(xb, xb, xa * xa);
        s = __builtin_elementwise_fma(gk, q, s);
      }
      bb[ch] = b;
      ss[ch] = s;
    }

    // barrier 1: previous iteration's hblur reads must finish before we
    // overwrite the single buffer (the reads->here gap absorbs the wait).
    lds_barrier();

    // plane-split stores, (u,v) interleave rebuilt from channel layout:
    // P0 = (u0,v0,u1,v1), P1 = (u2,v2,u3,v3); contiguous 16B-stride.
    {
      float4* P0 = reinterpret_cast<float4*>(bufUV[0]);
      float4* P1 = reinterpret_cast<float4*>(bufUV[1]);
      P0[tid + 2] = make_float4(bb[0].x, bb[2].x, bb[0].y, bb[2].y);
      P1[tid + 2] = make_float4(bb[1].x, bb[3].x, bb[1].y, bb[3].y);
      float4* Q0 = reinterpret_cast<float4*>(bufSQ[0]);
      float4* Q1 = reinterpret_cast<float4*>(bufSQ[1]);
      Q0[tid + 2] = make_float4(ss[0].x, ss[2].x, ss[0].y, ss[2].y);
      Q1[tid + 2] = make_float4(ss[1].x, ss[3].x, ss[1].y, ss[3].y);
    }
    lds_barrier();  // barrier 2: stores visible to all waves

    v2f huv[4], hsq[4];
    hblur(reinterpret_cast<const float4*>(bufUV[0]),
          reinterpret_cast<const float4*>(bufUV[1]), tid, huv);
    hblur(reinterpret_cast<const float4*>(bufSQ[0]),
          reinterpret_cast<const float4*>(bufSQ[1]), tid, hsq);

    // ssim: BU=mu1+mu2, BV=mu1-mu2, BU2=blur((x+y)^2), BV2=blur((x-y)^2)
#pragma unroll
    for (int m = 0; m < 4; ++m) {
      const float BU = huv[m].x, BV = huv[m].y;
      const float BU2 = hsq[m].x, BV2 = hsq[m].y;
      const float P = BU * BU, Q = BV * BV;
      const float PmQ = P - Q, PpQ = P + Q;
      const float An = fmaf(0.5f, PmQ, C1);                // 2*mu1*mu2+C1
      const float Bn = fmaf(0.5f, (BU2 - BV2) - PmQ, C2);  // 2*sigma12+C2
      const float Cd = fmaf(0.5f, PpQ, C1);                // mu1^2+mu2^2+C1
      const float Dd = fmaf(0.5f, (BU2 + BV2) - PpQ, C2);  // s1+s2+C2
      const float num = An * Bn;
      const float den = Cd * Dd;  // >= C1*C2 > 0
      float r = __builtin_amdgcn_rcpf(den);
      r = r * fmaf(-den, r, 2.f);  // one Newton step
      acc = fmaf(num, r, acc);
    }

    // shift the ring (b32 movs)
#pragma unroll
    for (int k = 0; k < 10; ++k)
#pragma unroll
      for (int c = 0; c < 4; ++c) ruv[k][c] = ruv[k + 1][c];
  }

  // block reduction -> global double accumulator
#pragma unroll
  for (int off = 32; off > 0; off >>= 1) acc += __shfl_down(acc, off, 64);
  if ((tid & 63) == 0) red[tid >> 6] = acc;
  __syncthreads();
  if (tid == 0) {
    float t = 0.f;
#pragma unroll
    for (int wv = 0; wv < BLOCK / 64; ++wv) t += red[wv];
    atomicAdd(ws, (double)t);
  }
}

__global__ void ssim_fin(const double* __restrict__ ws,
                         float* __restrict__ out) {
  out[0] =
      1.0f - (float)(ws[0] * (1.0 / ((double)NIMG * (double)W * (double)H)));
}

extern "C" void kernel_launch(void* const* d_in, const int* in_sizes, int n_in,
                              void* d_out, int out_size, void* d_ws,
                              size_t ws_size, hipStream_t stream) {
  const float* img1 = (const float*)d_in[0];
  const float* img2 = (const float*)d_in[1];
  float* out = (float*)d_out;
  double* ws = (double*)d_ws;

  hipMemsetAsync(d_ws, 0, sizeof(double), stream);
  ssim_main<<<NIMG * NSTRIP, BLOCK, 0, stream>>>(img1, img2, ws);
  ssim_fin<<<1, 1, 0, stream>>>(ws, out);
}

// Round 9
// 335.054 us; speedup vs baseline: 1.0519x; 1.0265x over previous
//
#include <hip/hip_runtime.h>

typedef float v2f __attribute__((ext_vector_type(2)));

namespace {
constexpr int W = 1024;
constexpr int H = 1024;
constexpr int NIMG = 32;
constexpr int SROWS = 32;            // output rows per block strip
constexpr int NSTRIP = H / SROWS;    // 32 -> grid 1024 = 4 blocks/CU
constexpr int BLOCK = 256;           // 256 threads * 4 cols = 1024 cols
// pair-array: 8 zero-pad pair-cols each side of 1024 -> 1040 v2f = 520 float4,
// split into two planes of 260 float4 at float4 granularity.
constexpr int PLANE4 = 260;          // float4 slots per plane

constexpr float C1 = 0.0004f;        // (0.01*2)^2
constexpr float C2 = 0.0036f;        // (0.03*2)^2

// normalized gaussian, sigma=1.5, win=11 (symmetric: GW[k]==GW[10-k])
constexpr float GW[11] = {
    0.00102838f, 0.00759876f, 0.03600077f, 0.10936070f, 0.21300554f,
    0.26601172f,
    0.21300554f, 0.10936070f, 0.03600077f, 0.00759876f, 0.00102838f};
}  // namespace

// ---- forced VOP3P packed-f32 (hipcc does not auto-emit v_pk_*_f32 from
// <2 x float>; each v2f op otherwise scalarizes to 2 VALU instrs). Non-
// volatile asm: compiler may schedule/CSE freely. Operands are 64-bit VGPR
// pairs (v2f is 8B; ds_read_b128 quads are even-aligned so float4 sub-pairs
// pass through with no extra movs).
__device__ __forceinline__ v2f pk_mul(v2f a, v2f b) {
  v2f d;
  asm("v_pk_mul_f32 %0, %1, %2" : "=v"(d) : "v"(a), "v"(b));
  return d;
}
__device__ __forceinline__ v2f pk_add(v2f a, v2f b) {
  v2f d;
  asm("v_pk_add_f32 %0, %1, %2" : "=v"(d) : "v"(a), "v"(b));
  return d;
}
__device__ __forceinline__ v2f pk_fma(v2f a, v2f b, v2f c) {
  v2f d;
  asm("v_pk_fma_f32 %0, %1, %2, %3" : "=v"(d) : "v"(a), "v"(b), "v"(c));
  return d;
}

// Block-wide barrier that only waits for LDS (lgkmcnt), NOT vmcnt: the pf
// global load stays in flight across barriers (no collective HBM drain).
__device__ __forceinline__ void lds_barrier() {
  asm volatile("s_waitcnt lgkmcnt(0)" ::: "memory");
  __builtin_amdgcn_s_barrier();
  asm volatile("" ::: "memory");
}

// Load one row, produce per-column packed pairs (u,v) = (x+y, x-y).
// y is block-uniform -> uniform branch, no per-lane masking.
__device__ __forceinline__ void load_uv(const float4* __restrict__ p1,
                                        const float4* __restrict__ p2, int y,
                                        int tid, v2f uv[4]) {
  if ((unsigned)y < (unsigned)H) {
    const float4 a = p1[y * (W / 4) + tid];
    const float4 b = p2[y * (W / 4) + tid];
    uv[0] = (v2f){a.x + b.x, a.x - b.x};
    uv[1] = (v2f){a.y + b.y, a.y - b.y};
    uv[2] = (v2f){a.z + b.z, a.z - b.z};
    uv[3] = (v2f){a.w + b.w, a.w - b.w};
  } else {
#pragma unroll
    for (int c = 0; c < 4; ++c) uv[c] = (v2f){0.f, 0.f};
  }
}

// 11-tap horizontal blur over a pre-paired 16-pair window read from the
// two conflict-free planes. t[s] holds pair-col 4t-6+s (buffer-relative).
// (All 8 float4 from LDS: register-passthrough variants spilled — LDS
// re-read is cheaper than scratch.) Weights g2[6] are hoisted v2f pairs.
__device__ __forceinline__ void hblur(const float4* __restrict__ P0,
                                      const float4* __restrict__ P1, int tid,
                                      const v2f* __restrict__ g2, v2f h[4]) {
  v2f t[16];
#pragma unroll
  for (int e = 0; e < 8; ++e) {
    // original pair-float4 j = 2t+1+e; odd j -> P0[(j-1)/2], even -> P1[j/2]
    const float4 r = (e & 1) ? P0[tid + (e + 1) / 2] : P1[tid + e / 2];
    t[2 * e + 0] = (v2f){r.x, r.y};
    t[2 * e + 1] = (v2f){r.z, r.w};
  }
#pragma unroll
  for (int m = 0; m < 4; ++m) {
    v2f s = pk_mul(g2[0], t[m + 1]);
#pragma unroll
    for (int k = 1; k < 11; ++k)
      s = pk_fma(g2[k < 6 ? k : 10 - k], t[m + 1 + k], s);
    h[m] = s;
  }
}

// Sum of SSIM map values over the strip; atomicAdd into ws[0] (double).
__global__ __launch_bounds__(BLOCK, 4) void ssim_main(
    const float* __restrict__ img1, const float* __restrict__ img2,
    double* __restrict__ ws) {
  // parity double-buffered, plane-split pair buffers:
  // bufUV = (blur_v(u), blur_v(v)) pairs; bufSQ = (blur_v(u^2), blur_v(v^2))
  __shared__ __align__(16) v2f bufUV[2][2][2 * PLANE4];
  __shared__ __align__(16) v2f bufSQ[2][2][2 * PLANE4];
  __shared__ float red[BLOCK / 64];

  const int tid = threadIdx.x;
  const int bid = blockIdx.x;
  const int img = bid / NSTRIP;
  const int strip = bid % NSTRIP;
  const int ys = strip * SROWS;

  const float4* p1 =
      reinterpret_cast<const float4*>(img1) + (size_t)img * (W / 4) * H;
  const float4* p2 =
      reinterpret_cast<const float4*>(img2) + (size_t)img * (W / 4) * H;

  // zero pad slots: planes P0/P1 slots {0,1,258,259}, both buffers+parities
  if (tid < 32) {
    const int par = tid & 1, b = (tid >> 1) & 1, pl = (tid >> 2) & 1,
              si = tid >> 3;
    const int slot = (si & 1) + ((si >> 1) ? 258 : 0);
    float4* p = reinterpret_cast<float4*>(b ? bufSQ[par][pl] : bufUV[par][pl]);
    p[slot] = make_float4(0.f, 0.f, 0.f, 0.f);
  }

  // hoisted packed weights (6 unique, symmetric) — VOP3P takes no literals
  v2f g2[6];
#pragma unroll
  for (int k = 0; k < 6; ++k) g2[k] = (v2f){GW[k], GW[k]};

  // shift ring: rows r-5..r+4 in ruv[0..9]; pf prefetches row r+5
  // (round-0 ordering: commit pf at loop top, issue next pf before vblur —
  //  the only schedule measured NOT to spill; reorderings cost 17-64MB scratch)
  v2f ruv[11][4];
#pragma unroll
  for (int s = 0; s < 10; ++s) load_uv(p1, p2, ys - 5 + s, tid, ruv[s]);
  v2f pf[4];
  load_uv(p1, p2, ys + 5, tid, pf);

  float acc = 0.f;

  for (int ii = 0; ii < SROWS; ++ii) {
    // commit prefetched row r+5, start prefetch of row r+6.
    // The new pf load stays in flight across lds_barrier() (no vmcnt drain)
    // and completes during hblur+ssim, waited per-wave at next commit.
#pragma unroll
    for (int c = 0; c < 4; ++c) ruv[10][c] = pf[c];
    load_uv(p1, p2, ys + ii + 6, tid, pf);

    // vertical 11-tap blur, symmetric-pair form (GW[k]==GW[10-k]):
    // 28 packed ops/col-pair, forced VOP3P.
    v2f buv[4], bsq[4];
#pragma unroll
    for (int c = 0; c < 4; ++c) {
      const v2f x5 = ruv[5][c];
      v2f b = pk_mul(g2[5], x5);
      v2f s = pk_mul(g2[5], pk_mul(x5, x5));
#pragma unroll
      for (int k = 0; k < 5; ++k) {
        const v2f xa = ruv[k][c];
        const v2f xb = ruv[10 - k][c];
        b = pk_fma(g2[k], pk_add(xa, xb), b);
        s = pk_fma(g2[k], pk_fma(xb, xb, pk_mul(xa, xa)), s);
      }
      buv[c] = b;
      bsq[c] = s;
    }

    const int par = ii & 1;
    // plane-split stores: pair-float4 F[2t+4] -> P0[t+2], F[2t+5] -> P1[t+2];
    // both contiguous 16B-stride -> conflict-free.
    {
      float4* P0 = reinterpret_cast<float4*>(bufUV[par][0]);
      float4* P1 = reinterpret_cast<float4*>(bufUV[par][1]);
      P0[tid + 2] = make_float4(buv[0].x, buv[0].y, buv[1].x, buv[1].y);
      P1[tid + 2] = make_float4(buv[2].x, buv[2].y, buv[3].x, buv[3].y);
      float4* Q0 = reinterpret_cast<float4*>(bufSQ[par][0]);
      float4* Q1 = reinterpret_cast<float4*>(bufSQ[par][1]);
      Q0[tid + 2] = make_float4(bsq[0].x, bsq[0].y, bsq[1].x, bsq[1].y);
      Q1[tid + 2] = make_float4(bsq[2].x, bsq[2].y, bsq[3].x, bsq[3].y);
    }
    lds_barrier();  // lgkmcnt-only: pf load NOT drained here

    v2f huv[4], hsq[4];
    hblur(reinterpret_cast<const float4*>(bufUV[par][0]),
          reinterpret_cast<const float4*>(bufUV[par][1]), tid, g2, huv);
    hblur(reinterpret_cast<const float4*>(bufSQ[par][0]),
          reinterpret_cast<const float4*>(bufSQ[par][1]), tid, g2, hsq);

    // ssim: BU=mu1+mu2, BV=mu1-mu2, BU2=blur((x+y)^2), BV2=blur((x-y)^2)
#pragma unroll
    for (int m = 0; m < 4; ++m) {
      const float BU = huv[m].x, BV = huv[m].y;
      const float BU2 = hsq[m].x, BV2 = hsq[m].y;
      const float P = BU * BU, Q = BV * BV;
      const float PmQ = P - Q, PpQ = P + Q;
      const float An = fmaf(0.5f, PmQ, C1);                // 2*mu1*mu2+C1
      const float Bn = fmaf(0.5f, (BU2 - BV2) - PmQ, C2);  // 2*sigma12+C2
      const float Cd = fmaf(0.5f, PpQ, C1);                // mu1^2+mu2^2+C1
      const float Dd = fmaf(0.5f, (BU2 + BV2) - PpQ, C2);  // s1+s2+C2
      const float num = An * Bn;
      const float den = Cd * Dd;  // >= C1*C2 > 0
      float r = __builtin_amdgcn_rcpf(den);
      r = r * fmaf(-den, r, 2.f);  // one Newton step
      acc = fmaf(num, r, acc);
    }

    // shift the ring (packed 64-bit moves)
#pragma unroll
    for (int k = 0; k < 10; ++k)
#pragma unroll
      for (int c = 0; c < 4; ++c) ruv[k][c] = ruv[k + 1][c];
  }

  // block reduction -> global double accumulator
#pragma unroll
  for (int off = 32; off > 0; off >>= 1) acc += __shfl_down(acc, off, 64);
  if ((tid & 63) == 0) red[tid >> 6] = acc;
  __syncthreads();
  if (tid == 0) {
    float t = 0.f;
#pragma unroll
    for (int wv = 0; wv < BLOCK / 64; ++wv) t += red[wv];
    atomicAdd(ws, (double)t);
  }
}

__global__ void ssim_fin(const double* __restrict__ ws,
                         float* __restrict__ out) {
  out[0] =
      1.0f - (float)(ws[0] * (1.0 / ((double)NIMG * (double)W * (double)H)));
}

extern "C" void kernel_launch(void* const* d_in, const int* in_sizes, int n_in,
                              void* d_out, int out_size, void* d_ws,
                              size_t ws_size, hipStream_t stream) {
  const float* img1 = (const float*)d_in[0];
  const float* img2 = (const float*)d_in[1];
  float* out = (float*)d_out;
  double* ws = (double*)d_ws;

  hipMemsetAsync(d_ws, 0, sizeof(double), stream);
  ssim_main<<<NIMG * NSTRIP, BLOCK, 0, stream>>>(img1, img2, ws);
  ssim_fin<<<1, 1, 0, stream>>>(ws, out);
}